// Round 5
// baseline (474.068 us; speedup 1.0000x reference)
//
#include <hip/hip_runtime.h>

namespace {

constexpr int kF = 8;       // fields
constexpr int kV = 100000;  // vocab
constexpr int kD = 16;      // latent dim
constexpr int kL = 50;      // seq length
constexpr int kNC = 7;      // categorical fields (1..7)
constexpr int kNP = 21;     // cat-cat pairs (i<j, both >=1)

__constant__ unsigned char cPI[kNP] = {1,1,1,1,1,1,2,2,2,2,2,3,3,3,3,4,4,4,5,5,6};
__constant__ unsigned char cPJ[kNP] = {2,3,4,5,6,7,3,4,5,6,7,4,5,6,7,5,6,7,6,7,7};

__global__ __launch_bounds__(256) void ffm_fwd(
    const int* __restrict__ xs,   // [B, L]
    const int* __restrict__ xc,   // [B, F-1]
    const float* __restrict__ T,  // [F, F, V, D]
    const float* __restrict__ Lt, // [F, V]
    const float* __restrict__ dw, // [F, 1]
    const float* __restrict__ db, // [1]
    float* __restrict__ out)      // [B]
{
    const int b = blockIdx.x;
    const int tid = threadIdx.x;

    __shared__ int sidx[kL];
    __shared__ int cat[kNC];
    __shared__ float w0[kNC][kD];   // e_{j->0} for j = 1..7
    __shared__ float r1[4], r2[4];

    // Phase 1: stage indices
    if (tid < kL) sidx[tid] = xs[b * kL + tid];
    if (tid >= 64 && tid < 64 + kNC) cat[tid - 64] = xc[b * kNC + (tid - 64)];
    __syncthreads();

    float facc = 0.f;  // cat-cat ffm partial
    float sacc = 0.f;  // seq ffm partial (to be scaled by 1/L)
    float zacc = 0.f;  // linear pre-relu partial (bias added at end)

    // Phase 2a (tid 0..27): stage w0[j][:] = T[j+1, 0, cat[j], :]
    if (tid < kNC * 4) {
        const int j = tid >> 2, q = tid & 3;
        const float4 v = *(const float4*)(
            T + ((size_t)((j + 1) * kF + 0) * kV + cat[j]) * kD + q * 4);
        *(float4*)(&w0[j][q * 4]) = v;
    }
    // Phase 2b (tid 32..115): 21 cat-cat pair dots, 4 lanes (float4) each
    {
        const int t = tid - 32;
        if (t >= 0 && t < kNP * 4) {
            const int p = t >> 2, q = t & 3;
            const int i = cPI[p], j = cPJ[p];
            const float4 a = *(const float4*)(
                T + ((size_t)(i * kF + j) * kV + cat[i - 1]) * kD + q * 4);
            const float4 c = *(const float4*)(
                T + ((size_t)(j * kF + i) * kV + cat[j - 1]) * kD + q * 4);
            facc += a.x * c.x + a.y * c.y + a.z * c.z + a.w * c.w;
        }
    }
    // Phase 2c: linear terms
    if (tid >= 128 && tid < 128 + kL) {
        zacc += Lt[sidx[tid - 128]] * dw[0] * (1.0f / kL);
    }
    if (tid >= 192 && tid < 192 + kNC) {
        const int f = tid - 192 + 1;
        zacc += Lt[(size_t)f * kV + cat[f - 1]] * dw[f];
    }
    __syncthreads();

    // Phase 3 (tid 0..223): seq pairs. Layout t = (l0, j, q); loop l += 8.
    if (tid < 224) {
        const int q = tid & 3;
        const int j = (tid >> 2) % kNC;   // field j+1
        const int l0 = tid / 28;
        const float4 w = *(const float4*)(&w0[j][q * 4]);
        const float* base = T + (size_t)(j + 1) * kV * kD + q * 4;
        for (int l = l0; l < kL; l += 8) {
            const float4 a = *(const float4*)(base + (size_t)sidx[l] * kD);
            sacc += a.x * w.x + a.y * w.y + a.z * w.z + a.w * w.w;
        }
    }

    // Reduction: two values across 256 threads
    float v1 = facc + sacc * (1.0f / kL);
    float v2 = zacc;
    #pragma unroll
    for (int o = 32; o > 0; o >>= 1) {
        v1 += __shfl_xor(v1, o, 64);
        v2 += __shfl_xor(v2, o, 64);
    }
    const int wave = tid >> 6;
    if ((tid & 63) == 0) { r1[wave] = v1; r2[wave] = v2; }
    __syncthreads();
    if (tid == 0) {
        const float ffm_sum = r1[0] + r1[1] + r1[2] + r1[3];
        float z = r2[0] + r2[1] + r2[2] + r2[3] + db[0];
        z = fmaxf(z, 0.f);
        const float x = z + ffm_sum;
        out[b] = 1.f / (1.f + expf(-x));
    }
}

} // namespace

extern "C" void kernel_launch(void* const* d_in, const int* in_sizes, int n_in,
                              void* d_out, int out_size, void* d_ws, size_t ws_size,
                              hipStream_t stream) {
    const int* xs = (const int*)d_in[0];
    const int* xc = (const int*)d_in[1];
    const float* T = (const float*)d_in[2];
    const float* Lt = (const float*)d_in[3];
    const float* dw = (const float*)d_in[4];
    const float* db = (const float*)d_in[5];
    float* out = (float*)d_out;
    const int B = in_sizes[0] / kL;  // 4096
    hipLaunchKernelGGL(ffm_fwd, dim3(B), dim3(256), 0, stream,
                       xs, xc, T, Lt, dw, db, out);
}